// Round 1
// baseline (526.467 us; speedup 1.0000x reference)
//
#include <hip/hip_runtime.h>
#include <cmath>

#define DF 128           // feature dim
#define TR 128           // gemm rows per block tile
#define KC 32            // gemm K chunk staged in LDS
#define PITCH 36         // LDS row pitch (32 data + 4 pad floats)

// ---------------------------------------------------------------------------
// Kernel 1: support[n][o] = sum_d X[n][d] * W[o][d] + b[o]
// Block: 256 threads, tile 128 rows x 128 cols, 8x8 register tile per thread.
// K staged in chunks of 32 floats; LDS rows XOR-rotated (multiples of 4
// floats, function of row index) so the 4 ty-groups of a wave hit distinct
// bank quads on the b128 reads.
// ---------------------------------------------------------------------------
__global__ __launch_bounds__(256, 1)
void gemm_bias_kernel(const float* __restrict__ X, const float* __restrict__ W,
                      const float* __restrict__ bias, float* __restrict__ S,
                      int N)
{
    __shared__ float Xs[TR * PITCH];   // 18.4 KB
    __shared__ float Ws[DF * PITCH];   // 18.4 KB

    const int t  = threadIdx.x;
    const int tx = t & 15;             // cols 8*tx .. 8*tx+7
    const int ty = t >> 4;             // rows 8*ty .. 8*ty+7
    const int r0 = blockIdx.x * TR;

    float acc[8][8];
    #pragma unroll
    for (int i = 0; i < 8; ++i)
        #pragma unroll
        for (int j = 0; j < 8; ++j) acc[i][j] = 0.f;

    for (int kc = 0; kc < DF; kc += KC) {
        // ---- stage X chunk: rows r0..r0+127, d in [kc, kc+32) ----
        #pragma unroll
        for (int l = 0; l < 4; ++l) {
            int idx = (l * 256 + t) * 4;          // [0, 128*32)
            int r   = idx >> 5;
            int dl  = idx & 31;
            int rot = ((r >> 2) & 7) * 4;
            float4 v = make_float4(0.f, 0.f, 0.f, 0.f);
            int gr = r0 + r;
            if (gr < N) v = *(const float4*)(X + (size_t)gr * DF + kc + dl);
            *(float4*)(Xs + r * PITCH + ((dl + rot) & 31)) = v;
        }
        // ---- stage W chunk: cols c=0..127, d in [kc, kc+32) ----
        #pragma unroll
        for (int l = 0; l < 4; ++l) {
            int idx = (l * 256 + t) * 4;
            int c   = idx >> 5;
            int dl  = idx & 31;
            int rot = ((c >> 3) & 7) * 4;
            float4 v = *(const float4*)(W + (size_t)c * DF + kc + dl);
            *(float4*)(Ws + c * PITCH + ((dl + rot) & 31)) = v;
        }
        __syncthreads();

        // ---- accumulate: 8 d-tiles of 4 ----
        #pragma unroll
        for (int dt = 0; dt < KC; dt += 4) {
            float4 xv[8], wv[8];
            #pragma unroll
            for (int i = 0; i < 8; ++i) {
                int r   = ty * 8 + i;
                int rot = ((r >> 2) & 7) * 4;
                xv[i] = *(const float4*)(Xs + r * PITCH + ((dt + rot) & 31));
            }
            #pragma unroll
            for (int j = 0; j < 8; ++j) {
                int c   = tx * 8 + j;
                int rot = ((c >> 3) & 7) * 4;
                wv[j] = *(const float4*)(Ws + c * PITCH + ((dt + rot) & 31));
            }
            #pragma unroll
            for (int i = 0; i < 8; ++i)
                #pragma unroll
                for (int j = 0; j < 8; ++j) {
                    acc[i][j] += xv[i].x * wv[j].x + xv[i].y * wv[j].y
                               + xv[i].z * wv[j].z + xv[i].w * wv[j].w;
                }
        }
        __syncthreads();
    }

    // ---- epilogue: add bias, store 2 x float4 per row ----
    float4 b0 = *(const float4*)(bias + tx * 8);
    float4 b1 = *(const float4*)(bias + tx * 8 + 4);
    #pragma unroll
    for (int i = 0; i < 8; ++i) {
        int gr = r0 + ty * 8 + i;
        if (gr < N) {
            float4 o0, o1;
            o0.x = acc[i][0] + b0.x; o0.y = acc[i][1] + b0.y;
            o0.z = acc[i][2] + b0.z; o0.w = acc[i][3] + b0.w;
            o1.x = acc[i][4] + b1.x; o1.y = acc[i][5] + b1.y;
            o1.z = acc[i][6] + b1.z; o1.w = acc[i][7] + b1.w;
            *(float4*)(S + (size_t)gr * DF + tx * 8)     = o0;
            *(float4*)(S + (size_t)gr * DF + tx * 8 + 4) = o1;
        }
    }
}

// ---------------------------------------------------------------------------
// Kernel 2: out[n][:] = tanh( sum_{e: adj_row[e]==n} adj_val[e]*support[adj_col[e]][:] )
// adj_row is sorted -> one wave per node, binary search the segment, no atomics.
// Lane L holds features 2L, 2L+1 (float2) -> each edge gather is one fully
// coalesced 512 B row read across the wave.
// ---------------------------------------------------------------------------
__global__ __launch_bounds__(256, 1)
void agg_tanh_kernel(const float* __restrict__ S, const int* __restrict__ arow,
                     const int* __restrict__ acol, const float* __restrict__ aval,
                     float* __restrict__ out, int Nn, int E)
{
    const int gw   = (int)((blockIdx.x * 256u + threadIdx.x) >> 6);  // node id
    const int lane = threadIdx.x & 63;
    if (gw >= Nn) return;
    const int n = gw;

    // lower_bound(arow, n) and lower_bound(arow, n+1)
    int lo = 0, hi = E;
    while (lo < hi) { int m = (lo + hi) >> 1; if (arow[m] < n) lo = m + 1; else hi = m; }
    const int start = lo;
    int lo2 = start, hi2 = E;
    while (lo2 < hi2) { int m = (lo2 + hi2) >> 1; if (arow[m] < n + 1) lo2 = m + 1; else hi2 = m; }
    const int end = lo2;

    float2 acc; acc.x = 0.f; acc.y = 0.f;
    for (int base = start; base < end; base += 64) {
        const int cnt = min(64, end - base);
        int   col = 0;
        float val = 0.f;
        if (base + lane < end) {
            col = acol[base + lane];
            val = aval[base + lane];
        }
        for (int i = 0; i < cnt; ++i) {
            const int   c = __shfl(col, i);
            const float v = __shfl(val, i);
            const float2 s = *(const float2*)(S + (size_t)c * DF + lane * 2);
            acc.x += v * s.x;
            acc.y += v * s.y;
        }
    }

    float2 o;
    o.x = tanhf(acc.x);
    o.y = tanhf(acc.y);
    *(float2*)(out + (size_t)n * DF + lane * 2) = o;
}

// ---------------------------------------------------------------------------
extern "C" void kernel_launch(void* const* d_in, const int* in_sizes, int n_in,
                              void* d_out, int out_size, void* d_ws, size_t ws_size,
                              hipStream_t stream)
{
    const float* X    = (const float*)d_in[0];   // [N, 128]
    const float* W    = (const float*)d_in[1];   // [128, 128]
    const float* bias = (const float*)d_in[2];   // [128]
    const int*   arow = (const int*)  d_in[3];   // [E] sorted
    const int*   acol = (const int*)  d_in[4];   // [E]
    const float* aval = (const float*)d_in[5];   // [E]
    float* out = (float*)d_out;
    float* S   = (float*)d_ws;                   // support scratch: N*128 fp32

    const int N = in_sizes[0] / DF;
    const int E = in_sizes[3];

    dim3 gb((N + TR - 1) / TR);
    gemm_bias_kernel<<<gb, 256, 0, stream>>>(X, W, bias, S, N);

    dim3 ga((unsigned)((N * 64 + 255) / 256));   // one 64-lane wave per node
    agg_tanh_kernel<<<ga, 256, 0, stream>>>(S, arow, acol, aval, out, N, E);
}